// Round 7
// baseline (118.364 us; speedup 1.0000x reference)
//
#include <hip/hip_runtime.h>

// INT8QuantizedLinear: B=16, S=512, IN=1024, OUT=4096  (M=8192, N=4096, K=1024)
// Harness widens integer inputs: weight arrives as const int* (int32 per value).
// Round 7: LDS-free fragment-direct GEMM. Operands total 12 MB (L2/L3-resident,
// FETCH_SIZE=17.8MB confirmed R6) -> read MFMA fragments straight from cache:
// per-lane global_load_dwordx4 covers 16 rows x 64B = full lines, perfectly
// coalesced. No LDS, no barriers, no waitcnt drains. Wave-tile 128x64, 4 waves
// per block share A rows (L1 x4 reuse); register double-buffer over K.

#define M_TOT 8192
#define N_TOT 4096
#define K_TOT 1024
#define QMAXF 127.0f

typedef int i32x4 __attribute__((ext_vector_type(4)));

// ---------------------------------------------------------------------------
// Kernel 0: fused prep (quant blocks [0,8192), weight repack [8192,12288))
// ---------------------------------------------------------------------------
__global__ __launch_bounds__(256) void prep(const float* __restrict__ x,
                                            const int* __restrict__ w32,
                                            signed char* __restrict__ xq,
                                            signed char* __restrict__ w8,
                                            float* __restrict__ iscale) {
  const int b = blockIdx.x;
  const int t = threadIdx.x;

  if (b < M_TOT) {
    const float4 v = reinterpret_cast<const float4*>(x)[(size_t)b * 256 + t];
    float m = fmaxf(fmaxf(fabsf(v.x), fabsf(v.y)), fmaxf(fabsf(v.z), fabsf(v.w)));
#pragma unroll
    for (int off = 32; off >= 1; off >>= 1) m = fmaxf(m, __shfl_xor(m, off, 64));

    __shared__ float wmax[4];
    const int lane = t & 63, wid = t >> 6;
    if (lane == 0) wmax[wid] = m;
    __syncthreads();
    const float amax = fmaxf(fmaxf(wmax[0], wmax[1]), fmaxf(wmax[2], wmax[3]));

    float scale = amax / QMAXF;
    if (scale == 0.0f) scale = 1.0f;

    int qi;
    signed char* qb = reinterpret_cast<signed char*>(&qi);
    qb[0] = (signed char)(int)fminf(fmaxf(rintf(v.x / scale), -128.0f), 127.0f);
    qb[1] = (signed char)(int)fminf(fmaxf(rintf(v.y / scale), -128.0f), 127.0f);
    qb[2] = (signed char)(int)fminf(fmaxf(rintf(v.z / scale), -128.0f), 127.0f);
    qb[3] = (signed char)(int)fminf(fmaxf(rintf(v.w / scale), -128.0f), 127.0f);
    reinterpret_cast<int*>(xq)[(size_t)b * 256 + t] = qi;

    if (t == 0) iscale[b] = scale;
  } else {
    const int i = (b - M_TOT) * 256 + t;
    const int4 v = reinterpret_cast<const int4*>(w32)[i];
    const int packed = (v.x & 0xFF) | ((v.y & 0xFF) << 8) |
                       ((v.z & 0xFF) << 16) | (v.w << 24);
    reinterpret_cast<int*>(w8)[i] = packed;
  }
}

// ---------------------------------------------------------------------------
// Kernel 1: LDS-free i8 GEMM. Block = 4 waves, tile 128(m) x 256(n); each
// wave owns 128x64. Fragments loaded per-lane direct from cache.
// ---------------------------------------------------------------------------
#define LOADK(A_, B_, kt)                                                      \
  _Pragma("unroll") for (int f = 0; f < 8; ++f)                                \
      A_[f] = *reinterpret_cast<const i32x4*>(Abase + f * 16 * K_TOT + (kt) * 64); \
  _Pragma("unroll") for (int g = 0; g < 4; ++g)                                \
      B_[g] = *reinterpret_cast<const i32x4*>(Bbase + g * 16 * K_TOT + (kt) * 64);

#define MFMAS(A_, B_)                                                          \
  __builtin_amdgcn_s_setprio(1);                                               \
  _Pragma("unroll") for (int f = 0; f < 8; ++f)                                \
  _Pragma("unroll") for (int g = 0; g < 4; ++g)                                \
      acc[f][g] = __builtin_amdgcn_mfma_i32_16x16x64_i8(A_[f], B_[g],          \
                                                        acc[f][g], 0, 0, 0);   \
  __builtin_amdgcn_s_setprio(0);

__global__ __launch_bounds__(256, 2) void int8_gemm(const signed char* __restrict__ xq,
                                                    const signed char* __restrict__ w,
                                                    const float* __restrict__ iscale,
                                                    const float* __restrict__ wscale,
                                                    const float* __restrict__ bias,
                                                    float* __restrict__ out) {
  const int t = threadIdx.x;
  const int lane = t & 63;
  const int wid = t >> 6;  // 0..3 -> n-offset wid*64 within block tile

  // XCD chunking: grid 1024 = 8 XCDs x 128. Per XCD: 16 m-tiles x 8 n-tiles
  // -> A-slice 2 MB + B-slice 2 MB = 4 MB, exactly one L2.
  const int bid = blockIdx.x;
  const int xcd = bid & 7, li = bid >> 3;        // li 0..127
  const int mt = (xcd >> 1) * 16 + (li >> 3);    // 0..63 (128-row m-tiles)
  const int nt = (xcd & 1) * 8 + (li & 7);       // 0..15 (256-col n-tiles)
  const int m0 = mt * 128;
  const int n0 = nt * 256 + wid * 64;

  // Fragment base addresses: lane lr=lane&15 -> row, kq=(lane>>4)*16 -> k sub.
  // One load instruction = 16 rows x 64 consecutive bytes = 16 full lines.
  const int lr = lane & 15;
  const int kq = (lane >> 4) * 16;
  const signed char* Abase = xq + (size_t)(m0 + lr) * K_TOT + kq;
  const signed char* Bbase = w + (size_t)(n0 + lr) * K_TOT + kq;

  i32x4 acc[8][4] = {};
  i32x4 a0[8], b0[4], a1[8], b1[4];

  LOADK(a0, b0, 0)
  LOADK(a1, b1, 1)

#pragma unroll
  for (int kt = 0; kt < K_TOT / 64; kt += 2) {
    MFMAS(a0, b0)
    if (kt + 2 < K_TOT / 64) LOADK(a0, b0, kt + 2)
    MFMAS(a1, b1)
    if (kt + 3 < K_TOT / 64) LOADK(a1, b1, kt + 3)
  }

  // ---- epilogue (validated R2-R6): col=lane&15, row=(lane>>4)*4+i ----
  const int col = lane & 15;
  const int rq = lane >> 4;
  float wsc[4], bv[4];
#pragma unroll
  for (int g = 0; g < 4; ++g) {
    const int gn = n0 + g * 16 + col;
    wsc[g] = wscale[gn];
    bv[g] = bias[gn];
  }
#pragma unroll
  for (int f = 0; f < 8; ++f) {
    const int gmb = m0 + f * 16 + rq * 4;
#pragma unroll
    for (int i = 0; i < 4; ++i) {
      const int gm = gmb + i;
      const float isc = iscale[gm];
      float* rowp = out + (size_t)gm * N_TOT + n0 + col;
#pragma unroll
      for (int g = 0; g < 4; ++g)
        __builtin_nontemporal_store((float)acc[f][g][i] * wsc[g] * isc + bv[g],
                                    rowp + g * 16);
    }
  }
}

// ---------------------------------------------------------------------------
extern "C" void kernel_launch(void* const* d_in, const int* in_sizes, int n_in,
                              void* d_out, int out_size, void* d_ws, size_t ws_size,
                              hipStream_t stream) {
  const float* x = (const float*)d_in[0];
  const int* w32 = (const int*)d_in[1];
  const float* wscale = (const float*)d_in[2];
  const float* bias = (const float*)d_in[3];
  float* out = (float*)d_out;

  signed char* xq = (signed char*)d_ws;                                    // 8 MB
  float* iscale = (float*)((char*)d_ws + (size_t)M_TOT * K_TOT);           // 32 KB
  signed char* w8 = (signed char*)((char*)d_ws + (size_t)M_TOT * K_TOT + M_TOT * 4);  // 4 MB

  const int pack_blocks = (N_TOT * K_TOT / 4) / 256;
  prep<<<M_TOT + pack_blocks, 256, 0, stream>>>(x, w32, xq, w8, iscale);
  int8_gemm<<<dim3((M_TOT / 128) * (N_TOT / 256)), 256, 0, stream>>>(xq, w8, iscale, wscale, bias, out);
}

// Round 8
// 71.142 us; speedup vs baseline: 1.6638x; 1.6638x over previous
//
#include <hip/hip_runtime.h>

// INT8QuantizedLinear: B=16, S=512, IN=1024, OUT=4096  (M=8192, N=4096, K=1024)
// Harness widens integer inputs: weight arrives as const int* (int32 per value).
// Round 8: R3 frame (256x256, 8 waves, BK=128, dbuf, issue-early stage, single
// __syncthreads per K-tile — proven 52us GEMM) with mfma_i32_32x32x32_i8
// (4404 TOPS ceiling, 2x per-issue pipe occupancy) and full-128B-line epilogue
// (32x32 C/D: col=lane&31 -> each store = 2 rows x 128B full lines).

#define M_TOT 8192
#define N_TOT 4096
#define K_TOT 1024
#define QMAXF 127.0f

#define BM 256
#define BN 256
#define BK 128              // i8 elems per LDS K-tile (128 B rows)
#define NKT (K_TOT / BK)    // 8

typedef int i32x4 __attribute__((ext_vector_type(4)));
typedef int i32x16 __attribute__((ext_vector_type(16)));

// ---------------------------------------------------------------------------
// Kernel 0: fused prep (quant blocks [0,8192), weight repack [8192,12288))
// ---------------------------------------------------------------------------
__global__ __launch_bounds__(256) void prep(const float* __restrict__ x,
                                            const int* __restrict__ w32,
                                            signed char* __restrict__ xq,
                                            signed char* __restrict__ w8,
                                            float* __restrict__ iscale) {
  const int b = blockIdx.x;
  const int t = threadIdx.x;

  if (b < M_TOT) {
    const float4 v = reinterpret_cast<const float4*>(x)[(size_t)b * 256 + t];
    float m = fmaxf(fmaxf(fabsf(v.x), fabsf(v.y)), fmaxf(fabsf(v.z), fabsf(v.w)));
#pragma unroll
    for (int off = 32; off >= 1; off >>= 1) m = fmaxf(m, __shfl_xor(m, off, 64));

    __shared__ float wmax[4];
    const int lane = t & 63, wid = t >> 6;
    if (lane == 0) wmax[wid] = m;
    __syncthreads();
    const float amax = fmaxf(fmaxf(wmax[0], wmax[1]), fmaxf(wmax[2], wmax[3]));

    float scale = amax / QMAXF;
    if (scale == 0.0f) scale = 1.0f;

    int qi;
    signed char* qb = reinterpret_cast<signed char*>(&qi);
    qb[0] = (signed char)(int)fminf(fmaxf(rintf(v.x / scale), -128.0f), 127.0f);
    qb[1] = (signed char)(int)fminf(fmaxf(rintf(v.y / scale), -128.0f), 127.0f);
    qb[2] = (signed char)(int)fminf(fmaxf(rintf(v.z / scale), -128.0f), 127.0f);
    qb[3] = (signed char)(int)fminf(fmaxf(rintf(v.w / scale), -128.0f), 127.0f);
    reinterpret_cast<int*>(xq)[(size_t)b * 256 + t] = qi;

    if (t == 0) iscale[b] = scale;
  } else {
    const int i = (b - M_TOT) * 256 + t;
    const int4 v = reinterpret_cast<const int4*>(w32)[i];
    const int packed = (v.x & 0xFF) | ((v.y & 0xFF) << 8) |
                       ((v.z & 0xFF) << 16) | (v.w << 24);
    reinterpret_cast<int*>(w8)[i] = packed;
  }
}

// ---------------------------------------------------------------------------
__device__ __forceinline__ void gload_lds16(const void* g, void* l) {
  __builtin_amdgcn_global_load_lds(
      (const __attribute__((address_space(1))) unsigned int*)g,
      (__attribute__((address_space(3))) unsigned int*)l, 16, 0, 0);
}

__global__ __launch_bounds__(512, 2) void int8_gemm(const signed char* __restrict__ xq,
                                                    const signed char* __restrict__ w,
                                                    const float* __restrict__ iscale,
                                                    const float* __restrict__ wscale,
                                                    const float* __restrict__ bias,
                                                    float* __restrict__ out) {
  __shared__ __attribute__((aligned(16))) signed char As[2][BM][BK];  // 64 KiB
  __shared__ __attribute__((aligned(16))) signed char Bs[2][BN][BK];  // 64 KiB

  const int t = threadIdx.x;
  const int lane = t & 63;
  const int wid = t >> 6;   // 0..7
  const int wm = wid >> 2;  // 0..1 (128-row half)
  const int wn = wid & 3;   // 0..3 (64-col quarter)

  // XCD-aware swizzle (R3's exact): 512 blocks, 64 contiguous per XCD
  const int bid = blockIdx.x;
  const int swz = (bid & 7) * 64 + (bid >> 3);
  const int m0 = (swz >> 4) * BM;
  const int n0 = (swz & 15) * BN;

  // staging: one pass = 512 thr x 16 B = 64 rows of 128 B; linear LDS dest,
  // pre-swizzled global source (involution byte ^ ((row&7)<<4))
  const int srow = t >> 3;
  const int scol_swz = ((t & 7) * 16) ^ ((srow & 7) << 4);

  auto stage = [&](int buf, int kt) {
    const int k0 = kt * BK;
#pragma unroll
    for (int c = 0; c < 4; ++c) {
      gload_lds16(xq + (size_t)(m0 + c * 64 + srow) * K_TOT + k0 + scol_swz,
                  &As[buf][c * 64][0] + t * 16);
      gload_lds16(w + (size_t)(n0 + c * 64 + srow) * K_TOT + k0 + scol_swz,
                  &Bs[buf][c * 64][0] + t * 16);
    }
  };

  // 32x32x32 fragment addressing: row = lane&31, k = (lane>>5)*16 + byte
  const int r32 = lane & 31;
  const int kh = (lane >> 5) * 16;

  i32x16 acc[4][2] = {};

  stage(0, 0);
  __syncthreads();  // drain prologue stage

  for (int kt = 0; kt < NKT; ++kt) {
    const int cur = kt & 1;
    if (kt + 1 < NKT) stage(cur ^ 1, kt + 1);  // issue next-tile loads first

#pragma unroll
    for (int ks = 0; ks < 4; ++ks) {           // 4 k-slices of 32
      const int kb = ks * 32 + kh;
      i32x4 a[4], b[2];
#pragma unroll
      for (int f = 0; f < 4; ++f) {
        const int r = wm * 128 + f * 32 + r32;
        a[f] = *reinterpret_cast<const i32x4*>(&As[cur][r][kb ^ ((r & 7) << 4)]);
      }
#pragma unroll
      for (int g = 0; g < 2; ++g) {
        const int r = wn * 64 + g * 32 + r32;
        b[g] = *reinterpret_cast<const i32x4*>(&Bs[cur][r][kb ^ ((r & 7) << 4)]);
      }
      __builtin_amdgcn_s_setprio(1);
#pragma unroll
      for (int f = 0; f < 4; ++f)
#pragma unroll
        for (int g = 0; g < 2; ++g)
          acc[f][g] = __builtin_amdgcn_mfma_i32_32x32x32_i8(a[f], b[g], acc[f][g], 0, 0, 0);
      __builtin_amdgcn_s_setprio(0);
    }
    __syncthreads();  // single per-tile drain: next tile landed, reads done
  }

  // ---- epilogue: 32x32 C/D layout (m74/m101, dtype-indep):
  // col = lane&31, row = (i&3) + 8*(i>>2) + 4*(lane>>5)
  const int col = lane & 31;
  const int h4 = (lane >> 5) * 4;
  float wsc[2], bv[2];
#pragma unroll
  for (int g = 0; g < 2; ++g) {
    const int gn = n0 + wn * 64 + g * 32 + col;
    wsc[g] = wscale[gn];
    bv[g] = bias[gn];
  }
#pragma unroll
  for (int f = 0; f < 4; ++f) {
    const int gmb = m0 + wm * 128 + f * 32;
#pragma unroll
    for (int i = 0; i < 16; ++i) {
      const int gm = gmb + (i & 3) + 8 * (i >> 2) + h4;
      const float isc = iscale[gm];
      float* rowp = out + (size_t)gm * N_TOT + n0 + wn * 64 + col;
#pragma unroll
      for (int g = 0; g < 2; ++g)
        __builtin_nontemporal_store((float)acc[f][g][i] * wsc[g] * isc + bv[g],
                                    rowp + g * 32);
    }
  }
}

// ---------------------------------------------------------------------------
extern "C" void kernel_launch(void* const* d_in, const int* in_sizes, int n_in,
                              void* d_out, int out_size, void* d_ws, size_t ws_size,
                              hipStream_t stream) {
  const float* x = (const float*)d_in[0];
  const int* w32 = (const int*)d_in[1];
  const float* wscale = (const float*)d_in[2];
  const float* bias = (const float*)d_in[3];
  float* out = (float*)d_out;

  signed char* xq = (signed char*)d_ws;                                    // 8 MB
  float* iscale = (float*)((char*)d_ws + (size_t)M_TOT * K_TOT);           // 32 KB
  signed char* w8 = (signed char*)((char*)d_ws + (size_t)M_TOT * K_TOT + M_TOT * 4);  // 4 MB

  const int pack_blocks = (N_TOT * K_TOT / 4) / 256;
  prep<<<M_TOT + pack_blocks, 256, 0, stream>>>(x, w32, xq, w8, iscale);
  int8_gemm<<<dim3((M_TOT / BM) * (N_TOT / BN)), 512, 0, stream>>>(xq, w8, iscale, wscale, bias, out);
}

// Round 9
// 68.674 us; speedup vs baseline: 1.7235x; 1.0359x over previous
//
#include <hip/hip_runtime.h>

// INT8QuantizedLinear: B=16, S=512, IN=1024, OUT=4096  (M=8192, N=4096, K=1024)
// Harness widens integer inputs: weight arrives as const int* (int32 per value).
// Round 9: OCCUPANCY. 128x128 tile, 4 waves, BK=64, double-buffered 32 KB LDS,
// __launch_bounds__(256,4) -> target 4 blocks/CU (16 waves/CU): cross-block
// overlap (m114 mechanism) instead of deeper intra-block phase scheduling
// (which regressed in R4/R5/R6/R8). One __syncthreads per K-step, issue-early
// stage, 16x16x64 MFMA, normal stores (no nontemporal).

#define M_TOT 8192
#define N_TOT 4096
#define K_TOT 1024
#define QMAXF 127.0f

#define BM 128
#define BN 128
#define BK 64               // i8 elems per LDS K-step (64 B rows)
#define NKT (K_TOT / BK)    // 16

typedef int i32x4 __attribute__((ext_vector_type(4)));

// ---------------------------------------------------------------------------
// Kernel 0: fused prep (quant blocks [0,8192), weight repack [8192,12288))
// ---------------------------------------------------------------------------
__global__ __launch_bounds__(256) void prep(const float* __restrict__ x,
                                            const int* __restrict__ w32,
                                            signed char* __restrict__ xq,
                                            signed char* __restrict__ w8,
                                            float* __restrict__ iscale) {
  const int b = blockIdx.x;
  const int t = threadIdx.x;

  if (b < M_TOT) {
    const float4 v = reinterpret_cast<const float4*>(x)[(size_t)b * 256 + t];
    float m = fmaxf(fmaxf(fabsf(v.x), fabsf(v.y)), fmaxf(fabsf(v.z), fabsf(v.w)));
#pragma unroll
    for (int off = 32; off >= 1; off >>= 1) m = fmaxf(m, __shfl_xor(m, off, 64));

    __shared__ float wmax[4];
    const int lane = t & 63, wid = t >> 6;
    if (lane == 0) wmax[wid] = m;
    __syncthreads();
    const float amax = fmaxf(fmaxf(wmax[0], wmax[1]), fmaxf(wmax[2], wmax[3]));

    float scale = amax / QMAXF;
    if (scale == 0.0f) scale = 1.0f;

    int qi;
    signed char* qb = reinterpret_cast<signed char*>(&qi);
    qb[0] = (signed char)(int)fminf(fmaxf(rintf(v.x / scale), -128.0f), 127.0f);
    qb[1] = (signed char)(int)fminf(fmaxf(rintf(v.y / scale), -128.0f), 127.0f);
    qb[2] = (signed char)(int)fminf(fmaxf(rintf(v.z / scale), -128.0f), 127.0f);
    qb[3] = (signed char)(int)fminf(fmaxf(rintf(v.w / scale), -128.0f), 127.0f);
    reinterpret_cast<int*>(xq)[(size_t)b * 256 + t] = qi;

    if (t == 0) iscale[b] = scale;
  } else {
    const int i = (b - M_TOT) * 256 + t;
    const int4 v = reinterpret_cast<const int4*>(w32)[i];
    const int packed = (v.x & 0xFF) | ((v.y & 0xFF) << 8) |
                       ((v.z & 0xFF) << 16) | (v.w << 24);
    reinterpret_cast<int*>(w8)[i] = packed;
  }
}

// ---------------------------------------------------------------------------
__device__ __forceinline__ void gload_lds16(const void* g, void* l) {
  __builtin_amdgcn_global_load_lds(
      (const __attribute__((address_space(1))) unsigned int*)g,
      (__attribute__((address_space(3))) unsigned int*)l, 16, 0, 0);
}

__global__ __launch_bounds__(256, 4) void int8_gemm(const signed char* __restrict__ xq,
                                                    const signed char* __restrict__ w,
                                                    const float* __restrict__ iscale,
                                                    const float* __restrict__ wscale,
                                                    const float* __restrict__ bias,
                                                    float* __restrict__ out) {
  __shared__ __attribute__((aligned(16))) signed char As[2][BM][BK];  // 16 KiB
  __shared__ __attribute__((aligned(16))) signed char Bs[2][BN][BK];  // 16 KiB

  const int t = threadIdx.x;
  const int lane = t & 63;
  const int wid = t >> 6;   // 0..3
  const int wm = wid >> 1;  // 0..1 (64-row half)
  const int wn = wid & 1;   // 0..1 (64-col half)

  // XCD chunking: 2048 blocks = 8 XCDs x 256; per XCD 16m x 16n 128-tiles
  // -> A-slice 2 MB + B-slice 2 MB resident in that XCD's L2.
  const int bid = blockIdx.x;
  const int xcd = bid & 7, li = bid >> 3;        // li 0..255
  const int mt = (xcd >> 1) * 16 + (li >> 4);    // 0..63
  const int nt = (xcd & 1) * 16 + (li & 15);     // 0..31
  const int m0 = mt * BM, n0 = nt * BN;

  // staging: one call = 256 thr x 16 B = 4 KB = 64 rows of 64 B; linear LDS
  // dest, pre-swizzled global source. 64B-row involution: byte^(((row>>1)&3)<<4)
  // (R6-validated algebra, 0 bank conflicts measured).
  const int srow = t >> 2;                                         // 0..63
  const int scol_swz = ((t & 3) * 16) ^ (((srow >> 1) & 3) << 4);

  auto stage = [&](int buf, int kt) {
    const int k0 = kt * BK;
#pragma unroll
    for (int c = 0; c < 2; ++c) {
      gload_lds16(xq + (size_t)(m0 + c * 64 + srow) * K_TOT + k0 + scol_swz,
                  &As[buf][c * 64][0] + t * 16);
      gload_lds16(w + (size_t)(n0 + c * 64 + srow) * K_TOT + k0 + scol_swz,
                  &Bs[buf][c * 64][0] + t * 16);
    }
  };

  // fragment reads: row = base + f*16 + (lane&15), k-slice = (lane>>4)*16
  const int lr = lane & 15;
  const int kq = (lane >> 4) * 16;
  auto rdA = [&](int buf, int f) -> i32x4 {
    const int r = wm * 64 + f * 16 + lr;
    return *reinterpret_cast<const i32x4*>(&As[buf][r][kq ^ (((r >> 1) & 3) << 4)]);
  };
  auto rdB = [&](int buf, int g) -> i32x4 {
    const int r = wn * 64 + g * 16 + lr;
    return *reinterpret_cast<const i32x4*>(&Bs[buf][r][kq ^ (((r >> 1) & 3) << 4)]);
  };

  i32x4 acc[4][4] = {};

  stage(0, 0);
  __syncthreads();  // drain prologue stage

  for (int kt = 0; kt < NKT; ++kt) {
    const int cur = kt & 1;
    if (kt + 1 < NKT) stage(cur ^ 1, kt + 1);  // issue next-step loads first

    i32x4 a[4], b[4];
#pragma unroll
    for (int f = 0; f < 4; ++f) a[f] = rdA(cur, f);
#pragma unroll
    for (int g = 0; g < 4; ++g) b[g] = rdB(cur, g);

    __builtin_amdgcn_s_setprio(1);
#pragma unroll
    for (int f = 0; f < 4; ++f)
#pragma unroll
      for (int g = 0; g < 4; ++g)
        acc[f][g] = __builtin_amdgcn_mfma_i32_16x16x64_i8(a[f], b[g], acc[f][g], 0, 0, 0);
    __builtin_amdgcn_s_setprio(0);

    __syncthreads();  // single per-step drain: next tile landed, reads done
  }

  // ---- epilogue (validated R2-R8): col=lane&15, row=(lane>>4)*4+i ----
  const int col = lane & 15;
  const int rq = lane >> 4;
  float wsc[4], bv[4];
#pragma unroll
  for (int g = 0; g < 4; ++g) {
    const int gn = n0 + wn * 64 + g * 16 + col;
    wsc[g] = wscale[gn];
    bv[g] = bias[gn];
  }
#pragma unroll
  for (int f = 0; f < 4; ++f) {
    const int gmb = m0 + wm * 64 + f * 16 + rq * 4;
#pragma unroll
    for (int i = 0; i < 4; ++i) {
      const int gm = gmb + i;
      const float isc = iscale[gm];
      float* rowp = out + (size_t)gm * N_TOT + n0 + wn * 64 + col;
#pragma unroll
      for (int g = 0; g < 4; ++g)
        rowp[g * 16] = (float)acc[f][g][i] * wsc[g] * isc + bv[g];
    }
  }
}

// ---------------------------------------------------------------------------
extern "C" void kernel_launch(void* const* d_in, const int* in_sizes, int n_in,
                              void* d_out, int out_size, void* d_ws, size_t ws_size,
                              hipStream_t stream) {
  const float* x = (const float*)d_in[0];
  const int* w32 = (const int*)d_in[1];
  const float* wscale = (const float*)d_in[2];
  const float* bias = (const float*)d_in[3];
  float* out = (float*)d_out;

  signed char* xq = (signed char*)d_ws;                                    // 8 MB
  float* iscale = (float*)((char*)d_ws + (size_t)M_TOT * K_TOT);           // 32 KB
  signed char* w8 = (signed char*)((char*)d_ws + (size_t)M_TOT * K_TOT + M_TOT * 4);  // 4 MB

  const int pack_blocks = (N_TOT * K_TOT / 4) / 256;
  prep<<<M_TOT + pack_blocks, 256, 0, stream>>>(x, w32, xq, w8, iscale);
  int8_gemm<<<dim3((M_TOT / BM) * (N_TOT / BN)), 256, 0, stream>>>(xq, w8, iscale, wscale, bias, out);
}

// Round 10
// 65.554 us; speedup vs baseline: 1.8056x; 1.0476x over previous
//
#include <hip/hip_runtime.h>

// INT8QuantizedLinear: B=16, S=512, IN=1024, OUT=4096  (M=8192, N=4096, K=1024)
// Harness widens integer inputs: weight arrives as const int* (int32 per value).
// Round 10: exact m201-style 4-phase/K-tile schedule on the R3 frame.
// Per phase: reads(future quadrant) -> stage(1 half-tile) -> barrier ->
// setprio MFMA16 setprio -> counted vmcnt -> barrier. Reads always issued one
// phase ahead of consumption. vmcnt ledger (2 loads per half-tile; stage order
// Ah0',Bh0',Bh1',Ah1'): end-P0=2, end-P1=none, end-P2=2, end-P3=2; never 0.

#define M_TOT 8192
#define N_TOT 4096
#define K_TOT 1024
#define QMAXF 127.0f

#define BM 256
#define BN 256
#define BK 128              // i8 elems per LDS K-tile (128 B rows)
#define NKT (K_TOT / BK)    // 8

typedef int i32x4 __attribute__((ext_vector_type(4)));

// ---------------------------------------------------------------------------
// Kernel 0: fused prep (quant blocks [0,8192), weight repack [8192,12288))
// ---------------------------------------------------------------------------
__global__ __launch_bounds__(256) void prep(const float* __restrict__ x,
                                            const int* __restrict__ w32,
                                            signed char* __restrict__ xq,
                                            signed char* __restrict__ w8,
                                            float* __restrict__ iscale) {
  const int b = blockIdx.x;
  const int t = threadIdx.x;

  if (b < M_TOT) {
    const float4 v = reinterpret_cast<const float4*>(x)[(size_t)b * 256 + t];
    float m = fmaxf(fmaxf(fabsf(v.x), fabsf(v.y)), fmaxf(fabsf(v.z), fabsf(v.w)));
#pragma unroll
    for (int off = 32; off >= 1; off >>= 1) m = fmaxf(m, __shfl_xor(m, off, 64));

    __shared__ float wmax[4];
    const int lane = t & 63, wid = t >> 6;
    if (lane == 0) wmax[wid] = m;
    __syncthreads();
    const float amax = fmaxf(fmaxf(wmax[0], wmax[1]), fmaxf(wmax[2], wmax[3]));

    float scale = amax / QMAXF;
    if (scale == 0.0f) scale = 1.0f;

    int qi;
    signed char* qb = reinterpret_cast<signed char*>(&qi);
    qb[0] = (signed char)(int)fminf(fmaxf(rintf(v.x / scale), -128.0f), 127.0f);
    qb[1] = (signed char)(int)fminf(fmaxf(rintf(v.y / scale), -128.0f), 127.0f);
    qb[2] = (signed char)(int)fminf(fmaxf(rintf(v.z / scale), -128.0f), 127.0f);
    qb[3] = (signed char)(int)fminf(fmaxf(rintf(v.w / scale), -128.0f), 127.0f);
    reinterpret_cast<int*>(xq)[(size_t)b * 256 + t] = qi;

    if (t == 0) iscale[b] = scale;
  } else {
    const int i = (b - M_TOT) * 256 + t;
    const int4 v = reinterpret_cast<const int4*>(w32)[i];
    const int packed = (v.x & 0xFF) | ((v.y & 0xFF) << 8) |
                       ((v.z & 0xFF) << 16) | (v.w << 24);
    reinterpret_cast<int*>(w8)[i] = packed;
  }
}

// ---------------------------------------------------------------------------
__device__ __forceinline__ void gload_lds16(const void* g, void* l) {
  __builtin_amdgcn_global_load_lds(
      (const __attribute__((address_space(1))) unsigned int*)g,
      (__attribute__((address_space(3))) unsigned int*)l, 16, 0, 0);
}

#define BARF asm volatile("s_barrier" ::: "memory")
#define VMW(n) asm volatile("s_waitcnt vmcnt(" #n ")" ::: "memory")

// 16-MFMA cluster for quadrant (MH, NH) using named reg sets
#define MFMA16(AS, BS, MH, NH)                                                \
  __builtin_amdgcn_s_setprio(1);                                              \
  _Pragma("unroll") for (int j = 0; j < 4; ++j)                               \
  _Pragma("unroll") for (int jb = 0; jb < 2; ++jb)                            \
  _Pragma("unroll") for (int ks = 0; ks < 2; ++ks)                            \
      acc[(MH) * 4 + j][(NH) * 2 + jb] = __builtin_amdgcn_mfma_i32_16x16x64_i8( \
          AS[j * 2 + ks], BS[jb * 2 + ks], acc[(MH) * 4 + j][(NH) * 2 + jb],  \
          0, 0, 0);                                                           \
  __builtin_amdgcn_s_setprio(0);

#define RD_A8(DST, BUF, MH)                                                   \
  _Pragma("unroll") for (int j = 0; j < 4; ++j)                               \
  _Pragma("unroll") for (int ks = 0; ks < 2; ++ks)                            \
      DST[j * 2 + ks] = rdA(BUF, (MH) * 4 + j, ks);

#define RD_B4(DST, BUF, NH)                                                   \
  _Pragma("unroll") for (int jb = 0; jb < 2; ++jb)                            \
  _Pragma("unroll") for (int ks = 0; ks < 2; ++ks)                            \
      DST[jb * 2 + ks] = rdB(BUF, (NH) * 2 + jb, ks);

__global__ __launch_bounds__(512, 2) void int8_gemm(const signed char* __restrict__ xq,
                                                    const signed char* __restrict__ w,
                                                    const float* __restrict__ iscale,
                                                    const float* __restrict__ wscale,
                                                    const float* __restrict__ bias,
                                                    float* __restrict__ out) {
  __shared__ __attribute__((aligned(16))) signed char As[2][BM][BK];  // 64 KiB
  __shared__ __attribute__((aligned(16))) signed char Bs[2][BN][BK];  // 64 KiB

  const int t = threadIdx.x;
  const int lane = t & 63;
  const int wid = t >> 6;   // 0..7
  const int wm = wid >> 2;  // 0..1
  const int wn = wid & 3;   // 0..3

  // XCD-aware swizzle (R3's): 512 blocks, 64 contiguous per XCD
  const int bid = blockIdx.x;
  const int swz = (bid & 7) * 64 + (bid >> 3);
  const int m0 = (swz >> 4) * BM;
  const int n0 = (swz & 15) * BN;

  // staging: one call = 512 thr x 16 B = 64 rows of 128 B; half-tile = 2 calls.
  // Linear LDS dest, pre-swizzled global source (involution byte^((row&7)<<4)).
  const int srow = t >> 3;
  const int scol_swz = ((t & 7) * 16) ^ ((srow & 7) << 4);

  auto stA = [&](int buf, int kt, int h) {
    const int k0 = kt * BK;
#pragma unroll
    for (int cc = 0; cc < 2; ++cc) {
      const int row = h * 128 + cc * 64 + srow;
      gload_lds16(xq + (size_t)(m0 + row) * K_TOT + k0 + scol_swz,
                  &As[buf][h * 128 + cc * 64][0] + t * 16);
    }
  };
  auto stB = [&](int buf, int kt, int h) {
    const int k0 = kt * BK;
#pragma unroll
    for (int cc = 0; cc < 2; ++cc) {
      const int row = h * 128 + cc * 64 + srow;
      gload_lds16(w + (size_t)(n0 + row) * K_TOT + k0 + scol_swz,
                  &Bs[buf][h * 128 + cc * 64][0] + t * 16);
    }
  };

  // interleaved mapping (validated R5/R6): m-frag f -> rows f*32 + wm*16,
  // n-frag g -> rows g*64 + wn*16; frags f<4 in Ah0, f>=4 in Ah1; g<2 Bh0.
  const int lr = lane & 15;
  const int kq = (lane >> 4) * 16;
  const int sx = (lr & 7) << 4;
  auto rdA = [&](int buf, int f, int ks) -> i32x4 {
    const int r = f * 32 + wm * 16 + lr;
    return *reinterpret_cast<const i32x4*>(&As[buf][r][(ks * 64 + kq) ^ sx]);
  };
  auto rdB = [&](int buf, int g, int ks) -> i32x4 {
    const int r = g * 64 + wn * 16 + lr;
    return *reinterpret_cast<const i32x4*>(&Bs[buf][r][(ks * 64 + kq) ^ sx]);
  };

  i32x4 acc[8][4] = {};
  i32x4 aE[8], aO[8], bC[4], bN[4];

  // prologue: stage tile0 half-tiles in order {Ah0,Bh0,Bh1,Ah1}; seal Ah0,Bh0;
  // read Q00 frags; seal Bh1 for P0's read.
  stA(0, 0, 0);
  stB(0, 0, 0);
  stB(0, 0, 1);
  stA(0, 0, 1);
  VMW(4); BARF;
  RD_A8(aE, 0, 0)
  RD_B4(bC, 0, 0)
  VMW(2); BARF;

  for (int U = 0; U < NKT - 1; ++U) {
    const int c = U & 1, nb = c ^ 1;
    // ---- P0: reads bN=Bh1(U); stage Ah0(U+1); MFMA Q00(aE,bC) ----
    RD_B4(bN, c, 1)
    stA(nb, U + 1, 0);
    BARF;
    MFMA16(aE, bC, 0, 0)
    VMW(2); BARF;          // seals Ah1(U) for P1's read
    // ---- P1: reads aO=Ah1(U); stage Bh0(U+1); MFMA Q01(aE,bN) ----
    RD_A8(aO, c, 1)
    stB(nb, U + 1, 0);
    BARF;
    MFMA16(aE, bN, 0, 1)
    BARF;                  // no vmcnt: P2 reads nothing
    // ---- P2: no reads; stage Bh1(U+1); MFMA Q10(aO,bC) ----
    stB(nb, U + 1, 1);
    BARF;
    MFMA16(aO, bC, 1, 0)
    VMW(2); BARF;          // seals Ah0(U+1),Bh0(U+1) for P3's reads
    // ---- P3: reads aE=Ah0(U+1),bC=Bh0(U+1); stage Ah1(U+1); Q11(aO,bN) ----
    RD_A8(aE, nb, 0)
    RD_B4(bC, nb, 0)
    stA(nb, U + 1, 1);
    BARF;
    MFMA16(aO, bN, 1, 1)
    VMW(2); BARF;          // seals Bh1(U+1) for next tile's P0 read
  }

  {  // ---- tail tile U = NKT-1 (no stages) ----
    const int c = (NKT - 1) & 1;
    RD_B4(bN, c, 1)
    BARF;
    MFMA16(aE, bC, 0, 0)
    VMW(0); BARF;          // drain: seals Ah1 for P1's read
    RD_A8(aO, c, 1)
    BARF;
    MFMA16(aE, bN, 0, 1)
    BARF;
    MFMA16(aO, bC, 1, 0)
    MFMA16(aO, bN, 1, 1)
  }

  // ---- epilogue (validated R5/R6): col=lane&15, row=(lane>>4)*4+i ----
  const int col = lane & 15;
  const int rq = lane >> 4;
  float wsc[4], bv[4];
#pragma unroll
  for (int g = 0; g < 4; ++g) {
    const int gn = n0 + g * 64 + wn * 16 + col;
    wsc[g] = wscale[gn];
    bv[g] = bias[gn];
  }
#pragma unroll
  for (int f = 0; f < 8; ++f) {
    const int gmb = m0 + f * 32 + wm * 16 + rq * 4;
#pragma unroll
    for (int i = 0; i < 4; ++i) {
      const int gm = gmb + i;
      const float isc = iscale[gm];
      float* rowp = out + (size_t)gm * N_TOT + n0 + wn * 16 + col;
#pragma unroll
      for (int g = 0; g < 4; ++g)
        rowp[g * 64] = (float)acc[f][g][i] * wsc[g] * isc + bv[g];
    }
  }
}

// ---------------------------------------------------------------------------
extern "C" void kernel_launch(void* const* d_in, const int* in_sizes, int n_in,
                              void* d_out, int out_size, void* d_ws, size_t ws_size,
                              hipStream_t stream) {
  const float* x = (const float*)d_in[0];
  const int* w32 = (const int*)d_in[1];
  const float* wscale = (const float*)d_in[2];
  const float* bias = (const float*)d_in[3];
  float* out = (float*)d_out;

  signed char* xq = (signed char*)d_ws;                                    // 8 MB
  float* iscale = (float*)((char*)d_ws + (size_t)M_TOT * K_TOT);           // 32 KB
  signed char* w8 = (signed char*)((char*)d_ws + (size_t)M_TOT * K_TOT + M_TOT * 4);  // 4 MB

  const int pack_blocks = (N_TOT * K_TOT / 4) / 256;
  prep<<<M_TOT + pack_blocks, 256, 0, stream>>>(x, w32, xq, w8, iscale);
  int8_gemm<<<dim3((M_TOT / BM) * (N_TOT / BN)), 512, 0, stream>>>(xq, w8, iscale, wscale, bias, out);
}